// Round 1
// 263.389 us; speedup vs baseline: 1.0684x; 1.0684x over previous
//
#include <hip/hip_runtime.h>
#include <math.h>

// Problem constants (B,S,D,H) = (4,2048,1024,16), HD=64
#define BATCH 4
#define SEQ   2048
#define DMODEL 1024
#define NHEAD 16
#define HDIM  64
#define MROWS (BATCH*SEQ)   // 8192

typedef unsigned short u16;
typedef unsigned int   u32;

using bf16x8 = __attribute__((ext_vector_type(8))) short;
using f32x4  = __attribute__((ext_vector_type(4))) float;
using f32x16 = __attribute__((ext_vector_type(16))) float;

__device__ __forceinline__ u16 f2bf(float f) {
    u32 u = __float_as_uint(f);
    u += 0x7fffu + ((u >> 16) & 1u);
    return (u16)(u >> 16);
}
__device__ __forceinline__ u32 pack2bf(float a, float b) {
    u32 ua = __float_as_uint(a); ua += 0x7fffu + ((ua >> 16) & 1u);
    u32 ub = __float_as_uint(b); ub += 0x7fffu + ((ub >> 16) & 1u);
    return (ua >> 16) | (ub & 0xffff0000u);
}

// async global->LDS, 16 B per lane; LDS dest = wave-uniform base + lane*16
#define GLOBAL_LOAD_LDS16(gp, lp)                                              \
    __builtin_amdgcn_global_load_lds(                                          \
        (const __attribute__((address_space(1))) void*)(gp),                   \
        (__attribute__((address_space(3))) void*)(lp), 16, 0, 0)

// ---------------------------------------------------------------------------
// Convert x (8.4M) + Wq/Wk/Wv/Wo (1M each) fp32 -> bf16 into contiguous dst.
// ---------------------------------------------------------------------------
__global__ __launch_bounds__(256) void convert_inputs(
    const float* __restrict__ x,  const float* __restrict__ wq,
    const float* __restrict__ wk, const float* __restrict__ wv,
    const float* __restrict__ wo, u16* __restrict__ dst)
{
    long long i4 = ((long long)blockIdx.x * 256 + threadIdx.x) * 4;
    const float* src; long long off;
    if (i4 < 8388608LL) { src = x; off = i4; }
    else {
        long long j = i4 - 8388608LL;
        int seg = (int)(j >> 20);
        off = j & 1048575LL;
        src = (seg == 0) ? wq : (seg == 1) ? wk : (seg == 2) ? wv : wo;
    }
    float4 v = *(const float4*)(src + off);
    u32 lo = (u32)f2bf(v.x) | ((u32)f2bf(v.y) << 16);
    u32 hi = (u32)f2bf(v.z) | ((u32)f2bf(v.w) << 16);
    *(uint2*)(dst + i4) = make_uint2(lo, hi);
}

// ---------------------------------------------------------------------------
// bf16 MFMA GEMM, deep-pipelined (T3+T4+T5):
//   tile BM=256 x BN=128, BK=64, 512 threads = 8 waves (4M x 2N, 64x64/wave).
//   LDS: 3-deep buffer rotation (3 x (256+128)x64 bf16 = 144 KiB).
//   Group t: 2 phases, each {8 ds_read_b128; 3 global_load_lds (tile t+2,
//   buf (t+2)%3); raw s_barrier; setprio(1); 16 MFMA; setprio(0); barrier}.
//   Group boundary: s_waitcnt vmcnt(6) (tile t+2's 6 loads stay in flight,
//   tile t+1 proven landed) -- never vmcnt(0) in steady state.
//   LDS rows = 64 shorts (128 B, 8 chunks); XOR swizzle chunk_phys =
//   chunk_log ^ (row&7), realized as pre-swizzled global source (linear
//   global_load_lds dest) + swizzled ds_read address.
//   Grid: XCD-aware (xcd = bx&7), bm-fastest: each XCD owns 4 bm-tiles
//   (2 MB of A, L2-resident) and streams W tiles.
//   QKV=1: N=3072 fused, seg = Q/K/V; epilogue RoPE(+0.125)/RoPE/plain bf16.
//   QKV=0: fp32 output + bias (final projection).
// ---------------------------------------------------------------------------
template<int QKV>
__global__ __launch_bounds__(512) void gemm_mfma(
    const u16* __restrict__ A,
    const u16* __restrict__ Wq_, const u16* __restrict__ Wk_, const u16* __restrict__ Wv_,
    const float* __restrict__ bq_, const float* __restrict__ bk_, const float* __restrict__ bv_,
    u16* __restrict__ Cq_, u16* __restrict__ Ck_, u16* __restrict__ Cv_,
    float* __restrict__ Cf)
{
    __shared__ u16 As[3 * 256 * 64];   // 96 KiB
    __shared__ u16 Ws[3 * 128 * 64];   // 48 KiB

    const int t    = threadIdx.x;
    const int lane = t & 63;
    const int w    = t >> 6;        // 0..7
    const int quad = lane >> 4;
    const int l15  = lane & 15;
    const int wm   = w >> 1;        // 0..3 (M)
    const int wn   = w & 1;         // 0..1 (N)

    // XCD-aware decode: xcd = bx&7; inner order bm-fastest, then n (seg in n).
    const int bx  = blockIdx.x;
    const int xcd = bx & 7;
    const int i_  = bx >> 3;
    const int bml = i_ & 3;
    const int n_  = i_ >> 2;                    // QKV: 0..23, proj: 0..7
    const int seg = (QKV ? (n_ >> 3) : 0);
    const int nn  = (QKV ? (n_ & 7) : n_);

    const u16*   W    = (seg == 0) ? Wq_ : (seg == 1) ? Wk_ : Wv_;
    const float* bias = (seg == 0) ? bq_ : (seg == 1) ? bk_ : bv_;
    u16*         Cb   = (seg == 0) ? Cq_ : (seg == 1) ? Ck_ : Cv_;

    const int bm   = (xcd * 4 + bml) * 256;
    const int bn   = nn * 128;
    const int wrow = wm * 64;
    const int wcol = wn * 64;

    // staging map: per issue a wave covers 8 rows; lane -> row 8w+(lane>>3),
    // phys chunk lane&7; source chunk = (lane&7) ^ (row&7) = (lane&7)^(lane>>3)
    const int sr8 = lane >> 3;
    const int scl = (lane & 7) ^ sr8;
    const u16* gA = A + (size_t)(bm + 8 * w + sr8) * DMODEL + scl * 8;
    const u16* gB = W + (size_t)(bn + 8 * w + sr8) * DMODEL + scl * 8;

#define STAGE_A(li, kt, bs)                                                    \
    GLOBAL_LOAD_LDS16(gA + (size_t)(li) * 64 * DMODEL + (kt) * 64,             \
                      &As[(bs) * 16384 + ((li) * 64 + 8 * w) * 64])
#define STAGE_B(li, kt, bs)                                                    \
    GLOBAL_LOAD_LDS16(gB + (size_t)(li) * 64 * DMODEL + (kt) * 64,             \
                      &Ws[(bs) * 8192 + ((li) * 64 + 8 * w) * 64])

    // ---- prologue: stage K-tiles 0 and 1 (6 loads each)
    STAGE_A(0, 0, 0); STAGE_A(1, 0, 0); STAGE_A(2, 0, 0); STAGE_A(3, 0, 0);
    STAGE_B(0, 0, 0); STAGE_B(1, 0, 0);
    STAGE_A(0, 1, 1); STAGE_A(1, 1, 1); STAGE_A(2, 1, 1); STAGE_A(3, 1, 1);
    STAGE_B(0, 1, 1); STAGE_B(1, 1, 1);
    asm volatile("s_waitcnt vmcnt(6)" ::: "memory");   // tile 0 landed
    __builtin_amdgcn_s_barrier();

    // frag-read chunk offsets (shorts): phase0 chunk quad^(row&7), phase1 ^4
    const int c0 = (quad ^ (l15 & 7)) * 8;
    const int c1 = c0 ^ 32;

    f32x4 acc[4][4] = {};

    int bsel = 0;
    for (int kt = 0; kt < DMODEL / 64; ++kt) {
        const u16* Ab = &As[bsel * 16384];
        const u16* Bb = &Ws[bsel * 8192];
        const int  ks = kt + 2;
        const int  sb = (bsel >= 1) ? bsel - 1 : 2;   // (bsel+2)%3
        const bool st = (ks < DMODEL / 64);

        bf16x8 af[4], bf[4];

        // ---- phase 0 (K-half 0)
        #pragma unroll
        for (int i = 0; i < 4; ++i)
            af[i] = *(const bf16x8*)&Ab[(wrow + 16 * i + l15) * 64 + c0];
        #pragma unroll
        for (int j = 0; j < 4; ++j)
            bf[j] = *(const bf16x8*)&Bb[(wcol + 16 * j + l15) * 64 + c0];
        if (st) { STAGE_A(0, ks, sb); STAGE_A(1, ks, sb); STAGE_A(2, ks, sb); }
        __builtin_amdgcn_s_barrier();
        __builtin_amdgcn_s_setprio(1);
        #pragma unroll
        for (int i = 0; i < 4; ++i)
            #pragma unroll
            for (int j = 0; j < 4; ++j)
                acc[i][j] = __builtin_amdgcn_mfma_f32_16x16x32_bf16(af[i], bf[j], acc[i][j], 0, 0, 0);
        __builtin_amdgcn_s_setprio(0);
        __builtin_amdgcn_s_barrier();

        // ---- phase 1 (K-half 1)
        #pragma unroll
        for (int i = 0; i < 4; ++i)
            af[i] = *(const bf16x8*)&Ab[(wrow + 16 * i + l15) * 64 + c1];
        #pragma unroll
        for (int j = 0; j < 4; ++j)
            bf[j] = *(const bf16x8*)&Bb[(wcol + 16 * j + l15) * 64 + c1];
        if (st) { STAGE_A(3, ks, sb); STAGE_B(0, ks, sb); STAGE_B(1, ks, sb); }
        __builtin_amdgcn_s_barrier();
        __builtin_amdgcn_s_setprio(1);
        #pragma unroll
        for (int i = 0; i < 4; ++i)
            #pragma unroll
            for (int j = 0; j < 4; ++j)
                acc[i][j] = __builtin_amdgcn_mfma_f32_16x16x32_bf16(af[i], bf[j], acc[i][j], 0, 0, 0);
        __builtin_amdgcn_s_setprio(0);
        // group boundary: tile kt+1 must be landed; tile kt+2's 6 loads
        // (just issued) are the only ones allowed to stay outstanding.
        if (st) asm volatile("s_waitcnt vmcnt(6)" ::: "memory");
        else    asm volatile("s_waitcnt vmcnt(0)" ::: "memory");
        __builtin_amdgcn_s_barrier();

        bsel = (bsel == 2) ? 0 : bsel + 1;
    }
#undef STAGE_A
#undef STAGE_B

    // ---- epilogue (identical fragment roles to the verified 128x128 kernel)
    float bv[4];
    #pragma unroll
    for (int j = 0; j < 4; j++) bv[j] = bias[bn + wcol + 16 * j + l15];

    if constexpr (QKV == 0) {
        #pragma unroll
        for (int i = 0; i < 4; i++)
            #pragma unroll
            for (int r = 0; r < 4; r++) {
                int mg = bm + wrow + 16 * i + quad * 4 + r;
                #pragma unroll
                for (int j = 0; j < 4; j++)
                    Cf[(size_t)mg * DMODEL + bn + wcol + 16 * j + l15] = acc[i][j][r] + bv[j];
            }
    } else {
        if (seg == 2) {
            #pragma unroll
            for (int i = 0; i < 4; i++)
                #pragma unroll
                for (int r = 0; r < 4; r++) {
                    int mg = bm + wrow + 16 * i + quad * 4 + r;
                    #pragma unroll
                    for (int j = 0; j < 4; j++)
                        Cb[(size_t)mg * DMODEL + bn + wcol + 16 * j + l15] = f2bf(acc[i][j][r] + bv[j]);
                }
        } else {
            // RoPE: wave's 64-col span = one head; pair (d, d+32) = j-tiles (j, j+2)
            const float qscale = (seg == 0) ? 0.125f : 1.0f;
            float inv[2];
            #pragma unroll
            for (int j = 0; j < 2; j++) {
                int d = 16 * j + l15;                              // 0..31
                inv[j] = exp2f(-(float)d * 0.4152410118609203f);   // 10000^(-d/32)
            }
            #pragma unroll
            for (int i = 0; i < 4; i++)
                #pragma unroll
                for (int r = 0; r < 4; r++) {
                    int mg = bm + wrow + 16 * i + quad * 4 + r;
                    int s  = mg & (SEQ - 1);
                    #pragma unroll
                    for (int j = 0; j < 2; j++) {
                        float f = (float)s * inv[j];
                        float sn, cs;
                        __sincosf(f, &sn, &cs);
                        float a1 = acc[i][j][r]     + bv[j];
                        float a2 = acc[i][j + 2][r] + bv[j + 2];
                        float o1 = (a1 * cs - a2 * sn) * qscale;
                        float o2 = (a2 * cs + a1 * sn) * qscale;
                        Cb[(size_t)mg * DMODEL + bn + wcol + 16 * j       + l15] = f2bf(o1);
                        Cb[(size_t)mg * DMODEL + bn + wcol + 16 * (j + 2) + l15] = f2bf(o2);
                    }
                }
        }
    }
}

// ---------------------------------------------------------------------------
// MFMA flash attention v2: 32x32x16 MFMA, 128 q-rows/block, max-free softmax.
// Wave w owns q rows [32w,32w+32). S^T = K*Q^T per 64-kr tile; exp; P via LDS
// (wave-private rows, no barrier); O += P@V with V staged transposed.
// All LDS tiles: 64-short rows, XOR swizzle phys_chunk = logical ^ (row&7).
// ---------------------------------------------------------------------------
__global__ __launch_bounds__(256) void attn_mfma(
    const u16* __restrict__ Q, const u16* __restrict__ K,
    const u16* __restrict__ V, u16* __restrict__ O)
{
    __shared__ u16 Qs[128 * 64];
    __shared__ u16 Ks[64 * 64];
    __shared__ u16 Vt[64 * 64];
    __shared__ u16 Ps[128 * 64];
    __shared__ float lS[128];

    const int t    = threadIdx.x;
    const int lane = t & 63;
    const int w    = t >> 6;
    const int l31  = lane & 31;
    const int hl   = lane >> 5;         // 0/1
    const int bid  = blockIdx.x;
    const int bh   = bid & 63;
    const int qt   = 15 - (bid >> 6);   // heavy q-tiles first
    const int h    = bh & (NHEAD - 1);
    const int b    = bh >> 4;
    const int q0   = qt * 128;

    const size_t gbase = ((size_t)b * SEQ) * DMODEL + h * HDIM;

    // ---- stage Q tile (128 rows) via global_load_lds, swizzled
    {
        int rl = lane >> 3, cp = lane & 7;
        int c  = cp ^ rl;                       // logical chunk
        #pragma unroll
        for (int i = 0; i < 4; i++) {
            int row = 32 * w + 8 * i + rl;
            GLOBAL_LOAD_LDS16(Q + gbase + (size_t)(q0 + row) * DMODEL + c * 8,
                              &Qs[(32 * w + 8 * i) * 64]);
        }
    }
    __syncthreads();

    // ---- hoist Q B-fragments (loop-invariant): B[k][n=q], k = hl*8+j+16s
    bf16x8 qf[4];
    {
        int row = 32 * w + l31;
        #pragma unroll
        for (int s = 0; s < 4; s++) {
            int c = (hl + 2 * s) ^ (row & 7);
            qf[s] = *(const bf16x8*)&Qs[row * 64 + c * 8];
        }
    }

    float lsum = 0.0f;
    f32x16 oacc[2] = {};

    const int ktn = 2 * qt + 2;
    for (int kt = 0; kt < ktn; kt++) {
        const int k0 = kt * 64;
        __syncthreads();   // protect Ks/Vt from previous iteration's readers

        // ---- stage K (64 rows) via global_load_lds, swizzled
        {
            int rl = lane >> 3, cp = lane & 7;
            int c  = cp ^ rl;
            #pragma unroll
            for (int i = 0; i < 2; i++) {
                int row = 16 * w + 8 * i + rl;
                GLOBAL_LOAD_LDS16(K + gbase + (size_t)(k0 + row) * DMODEL + c * 8,
                                  &Ks[(16 * w + 8 * i) * 64]);
            }
        }
        // ---- stage V transposed: Vt[d][j] = V[k0+j][d], swizzled pair-packed
        {
            int j0 = (t & 31) * 2, d0 = (t >> 5) * 8;
            uint4 va = *(const uint4*)(V + gbase + (size_t)(k0 + j0)     * DMODEL + d0);
            uint4 vb = *(const uint4*)(V + gbase + (size_t)(k0 + j0 + 1) * DMODEL + d0);
            const u16* pa = (const u16*)&va;
            const u16* pb = (const u16*)&vb;
            int jd = t & 31, pos = jd & 3, ch = jd >> 2;
            #pragma unroll
            for (int e = 0; e < 8; e++) {
                int row = d0 + e;
                int pcch = ch ^ (row & 7);
                *(u32*)&Vt[row * 64 + pcch * 8 + pos * 2] = (u32)pa[e] | ((u32)pb[e] << 16);
            }
        }
        __syncthreads();

        const bool act = (k0 <= q0 + 32 * w + 31);
        if (act) {
            const int qrow = 32 * w + l31;           // local q row
            const int qg   = q0 + qrow;              // global q row
            #pragma unroll
            for (int krh = 0; krh < 2; krh++) {
                const bool qact = (k0 + 32 * krh <= q0 + 32 * w + 31);
                if (!qact) {
                    // fully masked quadrant: P = 0
                    #pragma unroll
                    for (int g = 0; g < 4; g++)
                        #pragma unroll
                        for (int pp = 0; pp < 2; pp++) {
                            int kr = 32 * krh + 8 * g + 4 * hl + 2 * pp;
                            int jd = kr >> 1;
                            int pcc = (jd >> 2) ^ (qrow & 7);
                            *(u32*)&Ps[qrow * 64 + pcc * 8 + (jd & 3) * 2] = 0u;
                        }
                    continue;
                }
                // ---- S^T quadrant: D[m=kr][n=q]
                f32x16 s = {};
                #pragma unroll
                for (int stp = 0; stp < 4; stp++) {
                    int row = 32 * krh + l31;
                    int c   = (hl + 2 * stp) ^ (l31 & 7);
                    bf16x8 ka = *(const bf16x8*)&Ks[row * 64 + c * 8];
                    s = __builtin_amdgcn_mfma_f32_32x32x16_bf16(ka, qf[stp], s, 0, 0, 0);
                }
                // causal mask on diagonal-crossing tiles
                if (k0 + 32 * krh + 31 > q0 + 32 * w) {
                    #pragma unroll
                    for (int r = 0; r < 16; r++) {
                        int krg = k0 + 32 * krh + (r & 3) + 8 * (r >> 2) + 4 * hl;
                        if (krg > qg) s[r] = -1e30f;
                    }
                }
                // ---- exp (max-free), accumulate l, pack P to LDS
                float pv[16];
                #pragma unroll
                for (int r = 0; r < 16; r++) { pv[r] = __expf(s[r]); lsum += pv[r]; }
                #pragma unroll
                for (int g = 0; g < 4; g++)
                    #pragma unroll
                    for (int pp = 0; pp < 2; pp++) {
                        int kr = 32 * krh + 8 * g + 4 * hl + 2 * pp;
                        int jd = kr >> 1;
                        int pcc = (jd >> 2) ^ (qrow & 7);
                        *(u32*)&Ps[qrow * 64 + pcc * 8 + (jd & 3) * 2] =
                            pack2bf(pv[4 * g + 2 * pp], pv[4 * g + 2 * pp + 1]);
                    }
            }

            // ---- O += P @ V   (A = P rows q [wave-private], B = Vt rows d)
            #pragma unroll
            for (int stp = 0; stp < 4; stp++) {
                int c = (hl + 2 * stp) ^ (l31 & 7);
                bf16x8 pf = *(const bf16x8*)&Ps[qrow * 64 + c * 8];
                #pragma unroll
                for (int dh = 0; dh < 2; dh++) {
                    bf16x8 vf = *(const bf16x8*)&Vt[(32 * dh + l31) * 64 + c * 8];
                    oacc[dh] = __builtin_amdgcn_mfma_f32_32x32x16_bf16(pf, vf, oacc[dh], 0, 0, 0);
                }
            }
        }
    }

    // ---- finalize l (cross-half reduce, through LDS to reindex q)
    lsum += __shfl_xor(lsum, 32, 64);
    if (lane < 32) lS[32 * w + lane] = lsum;
    __syncthreads();

    // ---- writeout: O / l   (C layout: col=l31=d-local, row=(r&3)+8*(r>>2)+4*hl)
    #pragma unroll
    for (int g = 0; g < 4; g++) {
        f32x4 lv = *(const f32x4*)&lS[32 * w + 8 * g + 4 * hl];
        #pragma unroll
        for (int rr = 0; rr < 4; rr++) {
            int qg = q0 + 32 * w + rr + 8 * g + 4 * hl;
            float inv = 1.0f / lv[rr];
            #pragma unroll
            for (int dh = 0; dh < 2; dh++) {
                float o = oacc[dh][4 * g + rr] * inv;
                O[gbase + (size_t)qg * DMODEL + 32 * dh + l31] = f2bf(o);
            }
        }
    }
}

// ---------------------------------------------------------------------------
extern "C" void kernel_launch(void* const* d_in, const int* in_sizes, int n_in,
                              void* d_out, int out_size, void* d_ws, size_t ws_size,
                              hipStream_t stream)
{
    const float* x  = (const float*)d_in[0];
    const float* Wq = (const float*)d_in[1];
    const float* bq = (const float*)d_in[2];
    const float* Wk = (const float*)d_in[3];
    const float* bk = (const float*)d_in[4];
    const float* Wv = (const float*)d_in[5];
    const float* bv = (const float*)d_in[6];
    const float* Wo = (const float*)d_in[7];
    const float* bo = (const float*)d_in[8];

    u16* wsp = (u16*)d_ws;
    u16* xb  = wsp;                    // 8388608
    u16* Wqb = wsp + 8388608;          // 1048576 each
    u16* Wkb = Wqb + 1048576;
    u16* Wvb = Wkb + 1048576;
    u16* Wob = Wvb + 1048576;
    u16* Qb  = Wob + 1048576;          // 8388608 each
    u16* Kb  = Qb + 8388608;
    u16* Vb  = Kb + 8388608;
    u16* Ab  = Vb + 8388608;

    convert_inputs<<<12288, 256, 0, stream>>>(x, Wq, Wk, Wv, Wo, xb);

    gemm_mfma<1><<<768, 512, 0, stream>>>(xb, Wqb, Wkb, Wvb, bq, bk, bv,
                                          Qb, Kb, Vb, nullptr);

    attn_mfma<<<1024, 256, 0, stream>>>(Qb, Kb, Vb, Ab);

    gemm_mfma<0><<<256, 512, 0, stream>>>(Ab, Wob, nullptr, nullptr, bo, nullptr, nullptr,
                                          nullptr, nullptr, nullptr, (float*)d_out);
}

// Round 2
// 254.618 us; speedup vs baseline: 1.1052x; 1.0345x over previous
//
#include <hip/hip_runtime.h>
#include <math.h>

// Problem constants (B,S,D,H) = (4,2048,1024,16), HD=64
#define BATCH 4
#define SEQ   2048
#define DMODEL 1024
#define NHEAD 16
#define HDIM  64
#define MROWS (BATCH*SEQ)   // 8192

typedef unsigned short u16;
typedef unsigned int   u32;

using bf16x8 = __attribute__((ext_vector_type(8))) short;
using f32x4  = __attribute__((ext_vector_type(4))) float;
using f32x16 = __attribute__((ext_vector_type(16))) float;
using u32x4  = __attribute__((ext_vector_type(4))) unsigned int;

__device__ __forceinline__ u16 f2bf(float f) {
    u32 u = __float_as_uint(f);
    u += 0x7fffu + ((u >> 16) & 1u);
    return (u16)(u >> 16);
}
__device__ __forceinline__ u32 pack2bf(float a, float b) {
    u32 ua = __float_as_uint(a); ua += 0x7fffu + ((ua >> 16) & 1u);
    u32 ub = __float_as_uint(b); ub += 0x7fffu + ((ub >> 16) & 1u);
    return (ua >> 16) | (ub & 0xffff0000u);
}
// packed f32->bf16x2 via HW instruction (src0 -> low half)
__device__ __forceinline__ u32 cvtpk(float a, float b) {
    u32 r;
    asm("v_cvt_pk_bf16_f32 %0, %1, %2" : "=v"(r) : "v"(a), "v"(b));
    return r;
}
// swap upper 32 lanes of a with lower 32 lanes of b
#define PLSWAP(a, b) asm("v_permlane32_swap_b32 %0, %1" : "+v"(a), "+v"(b))

// async global->LDS, 16 B per lane; LDS dest = wave-uniform base + lane*16
#define GLOBAL_LOAD_LDS16(gp, lp)                                              \
    __builtin_amdgcn_global_load_lds(                                          \
        (const __attribute__((address_space(1))) void*)(gp),                   \
        (__attribute__((address_space(3))) void*)(lp), 16, 0, 0)

// ---------------------------------------------------------------------------
// Convert x (8.4M) + Wq/Wk/Wv/Wo (1M each) fp32 -> bf16 into contiguous dst.
// ---------------------------------------------------------------------------
__global__ __launch_bounds__(256) void convert_inputs(
    const float* __restrict__ x,  const float* __restrict__ wq,
    const float* __restrict__ wk, const float* __restrict__ wv,
    const float* __restrict__ wo, u16* __restrict__ dst)
{
    long long i4 = ((long long)blockIdx.x * 256 + threadIdx.x) * 4;
    const float* src; long long off;
    if (i4 < 8388608LL) { src = x; off = i4; }
    else {
        long long j = i4 - 8388608LL;
        int seg = (int)(j >> 20);
        off = j & 1048575LL;
        src = (seg == 0) ? wq : (seg == 1) ? wk : (seg == 2) ? wv : wo;
    }
    float4 v = *(const float4*)(src + off);
    u32 lo = (u32)f2bf(v.x) | ((u32)f2bf(v.y) << 16);
    u32 hi = (u32)f2bf(v.z) | ((u32)f2bf(v.w) << 16);
    *(uint2*)(dst + i4) = make_uint2(lo, hi);
}

// ---------------------------------------------------------------------------
// bf16 MFMA GEMM, deep-pipelined (T3+T4+T5): BM=256 x BN=128, BK=64,
// 512 threads = 8 waves (4M x 2N). 3-deep LDS rotation, counted vmcnt(6).
// QKV=1: N=3072 fused, seg = Q/K/V. Q epilogue: RoPE * (0.125*log2e) so
// attention can use exp2 directly. K: RoPE. V: TRANSPOSED store
// V^T[b][h][d][s] via LDS bounce (attention stages it with global_load_lds).
// QKV=0: fp32 output + bias (final projection).
// ---------------------------------------------------------------------------
template<int QKV>
__global__ __launch_bounds__(512) void gemm_mfma(
    const u16* __restrict__ A,
    const u16* __restrict__ Wq_, const u16* __restrict__ Wk_, const u16* __restrict__ Wv_,
    const float* __restrict__ bq_, const float* __restrict__ bk_, const float* __restrict__ bv_,
    u16* __restrict__ Cq_, u16* __restrict__ Ck_, u16* __restrict__ Cv_,
    float* __restrict__ Cf)
{
    __shared__ u16 As[3 * 256 * 64];   // 96 KiB
    __shared__ u16 Ws[3 * 128 * 64];   // 48 KiB

    const int t    = threadIdx.x;
    const int lane = t & 63;
    const int w    = t >> 6;        // 0..7
    const int quad = lane >> 4;
    const int l15  = lane & 15;
    const int wm   = w >> 1;        // 0..3 (M)
    const int wn   = w & 1;         // 0..1 (N)

    const int bx  = blockIdx.x;
    const int xcd = bx & 7;
    const int i_  = bx >> 3;
    const int bml = i_ & 3;
    const int n_  = i_ >> 2;                    // QKV: 0..23, proj: 0..7
    const int seg = (QKV ? (n_ >> 3) : 0);
    const int nn  = (QKV ? (n_ & 7) : n_);

    const u16*   W    = (seg == 0) ? Wq_ : (seg == 1) ? Wk_ : Wv_;
    const float* bias = (seg == 0) ? bq_ : (seg == 1) ? bk_ : bv_;
    u16*         Cb   = (seg == 0) ? Cq_ : (seg == 1) ? Ck_ : Cv_;

    const int bm   = (xcd * 4 + bml) * 256;
    const int bn   = nn * 128;
    const int wrow = wm * 64;
    const int wcol = wn * 64;

    // staging map: lane -> row 8w+(lane>>3), phys chunk lane&7,
    // source chunk = (lane&7)^(row&7)
    const int sr8 = lane >> 3;
    const int scl = (lane & 7) ^ sr8;
    const u16* gA = A + (size_t)(bm + 8 * w + sr8) * DMODEL + scl * 8;
    const u16* gB = W + (size_t)(bn + 8 * w + sr8) * DMODEL + scl * 8;

#define STAGE_A(li, kt, bs)                                                    \
    GLOBAL_LOAD_LDS16(gA + (size_t)(li) * 64 * DMODEL + (kt) * 64,             \
                      &As[(bs) * 16384 + ((li) * 64 + 8 * w) * 64])
#define STAGE_B(li, kt, bs)                                                    \
    GLOBAL_LOAD_LDS16(gB + (size_t)(li) * 64 * DMODEL + (kt) * 64,             \
                      &Ws[(bs) * 8192 + ((li) * 64 + 8 * w) * 64])

    // ---- prologue: stage K-tiles 0 and 1 (6 loads each)
    STAGE_A(0, 0, 0); STAGE_A(1, 0, 0); STAGE_A(2, 0, 0); STAGE_A(3, 0, 0);
    STAGE_B(0, 0, 0); STAGE_B(1, 0, 0);
    STAGE_A(0, 1, 1); STAGE_A(1, 1, 1); STAGE_A(2, 1, 1); STAGE_A(3, 1, 1);
    STAGE_B(0, 1, 1); STAGE_B(1, 1, 1);
    asm volatile("s_waitcnt vmcnt(6)" ::: "memory");   // tile 0 landed
    __builtin_amdgcn_s_barrier();

    const int c0 = (quad ^ (l15 & 7)) * 8;
    const int c1 = c0 ^ 32;

    f32x4 acc[4][4] = {};

    int bsel = 0;
    for (int kt = 0; kt < DMODEL / 64; ++kt) {
        const u16* Ab = &As[bsel * 16384];
        const u16* Bb = &Ws[bsel * 8192];
        const int  ks = kt + 2;
        const int  sb = (bsel >= 1) ? bsel - 1 : 2;   // (bsel+2)%3
        const bool st = (ks < DMODEL / 64);

        bf16x8 af[4], bf[4];

        // ---- phase 0 (K-half 0)
        #pragma unroll
        for (int i = 0; i < 4; ++i)
            af[i] = *(const bf16x8*)&Ab[(wrow + 16 * i + l15) * 64 + c0];
        #pragma unroll
        for (int j = 0; j < 4; ++j)
            bf[j] = *(const bf16x8*)&Bb[(wcol + 16 * j + l15) * 64 + c0];
        if (st) { STAGE_A(0, ks, sb); STAGE_A(1, ks, sb); STAGE_A(2, ks, sb); }
        __builtin_amdgcn_s_barrier();
        __builtin_amdgcn_s_setprio(1);
        #pragma unroll
        for (int i = 0; i < 4; ++i)
            #pragma unroll
            for (int j = 0; j < 4; ++j)
                acc[i][j] = __builtin_amdgcn_mfma_f32_16x16x32_bf16(af[i], bf[j], acc[i][j], 0, 0, 0);
        __builtin_amdgcn_s_setprio(0);
        __builtin_amdgcn_s_barrier();

        // ---- phase 1 (K-half 1)
        #pragma unroll
        for (int i = 0; i < 4; ++i)
            af[i] = *(const bf16x8*)&Ab[(wrow + 16 * i + l15) * 64 + c1];
        #pragma unroll
        for (int j = 0; j < 4; ++j)
            bf[j] = *(const bf16x8*)&Bb[(wcol + 16 * j + l15) * 64 + c1];
        if (st) { STAGE_A(3, ks, sb); STAGE_B(0, ks, sb); STAGE_B(1, ks, sb); }
        __builtin_amdgcn_s_barrier();
        __builtin_amdgcn_s_setprio(1);
        #pragma unroll
        for (int i = 0; i < 4; ++i)
            #pragma unroll
            for (int j = 0; j < 4; ++j)
                acc[i][j] = __builtin_amdgcn_mfma_f32_16x16x32_bf16(af[i], bf[j], acc[i][j], 0, 0, 0);
        __builtin_amdgcn_s_setprio(0);
        if (st) asm volatile("s_waitcnt vmcnt(6)" ::: "memory");
        else    asm volatile("s_waitcnt vmcnt(0)" ::: "memory");
        __builtin_amdgcn_s_barrier();

        bsel = (bsel == 2) ? 0 : bsel + 1;
    }
#undef STAGE_A
#undef STAGE_B

    // ---- epilogue
    float bv[4];
    #pragma unroll
    for (int j = 0; j < 4; j++) bv[j] = bias[bn + wcol + 16 * j + l15];

    if constexpr (QKV == 0) {
        #pragma unroll
        for (int i = 0; i < 4; i++)
            #pragma unroll
            for (int r = 0; r < 4; r++) {
                int mg = bm + wrow + 16 * i + quad * 4 + r;
                #pragma unroll
                for (int j = 0; j < 4; j++)
                    Cf[(size_t)mg * DMODEL + bn + wcol + 16 * j + l15] = acc[i][j][r] + bv[j];
            }
    } else {
        if (seg == 2) {
            // ---- V^T store: transpose the 256(s) x 128(d) tile via LDS.
            // T logical [row=d 0..127][col=s 0..255] bf16, byte-swizzled
            // within each 512-B row: byte ^= (row&3)<<4 (16-B granular).
            u16* T = As;   // reuse, 64 KiB of 96
            #pragma unroll
            for (int i = 0; i < 4; i++) {
                #pragma unroll
                for (int j = 0; j < 4; j++) {
                    int col = wrow + 16 * i + quad * 4;   // s-local (r adds 0..3)
                    int row = wcol + 16 * j + l15;        // d-local 0..127
                    u32 lo = pack2bf(acc[i][j][0] + bv[j], acc[i][j][1] + bv[j]);
                    u32 hi = pack2bf(acc[i][j][2] + bv[j], acc[i][j][3] + bv[j]);
                    *(uint2*)((char*)T + row * 512 + ((col * 2) ^ ((row & 3) << 4)))
                        = make_uint2(lo, hi);
                }
            }
            __syncthreads();
            {
                int row  = t >> 2, colc = t & 3;          // 128 rows x 4 chunks
                int hgl  = (bn + row) >> 6;
                int dl   = (bn + row) & 63;
                int bb   = bm >> 11;
                size_t obase = (((size_t)(bb * NHEAD + hgl)) * HDIM + dl) * SEQ
                             + (bm & (SEQ - 1)) + colc * 64;
                #pragma unroll
                for (int k = 0; k < 8; k++) {
                    uint4 vv = *(const uint4*)((const char*)T + row * 512
                                 + ((colc * 128 + k * 16) ^ ((row & 3) << 4)));
                    *(uint4*)(Cb + obase + k * 8) = vv;
                }
            }
        } else {
            // RoPE: wave's 64-col span = one head; pair (d, d+32) = j-tiles (j, j+2)
            // Q additionally scaled by 0.125 * log2(e) so attn uses exp2 directly.
            const float qscale = (seg == 0) ? 0.18033688011112042f : 1.0f;
            float inv[2];
            #pragma unroll
            for (int j = 0; j < 2; j++) {
                int d = 16 * j + l15;                              // 0..31
                inv[j] = exp2f(-(float)d * 0.4152410118609203f);   // 10000^(-d/32)
            }
            #pragma unroll
            for (int i = 0; i < 4; i++)
                #pragma unroll
                for (int r = 0; r < 4; r++) {
                    int mg = bm + wrow + 16 * i + quad * 4 + r;
                    int s  = mg & (SEQ - 1);
                    #pragma unroll
                    for (int j = 0; j < 2; j++) {
                        float f = (float)s * inv[j];
                        float sn, cs;
                        __sincosf(f, &sn, &cs);
                        float a1 = acc[i][j][r]     + bv[j];
                        float a2 = acc[i][j + 2][r] + bv[j + 2];
                        float o1 = (a1 * cs - a2 * sn) * qscale;
                        float o2 = (a2 * cs + a1 * sn) * qscale;
                        Cb[(size_t)mg * DMODEL + bn + wcol + 16 * j       + l15] = f2bf(o1);
                        Cb[(size_t)mg * DMODEL + bn + wcol + 16 * (j + 2) + l15] = f2bf(o2);
                    }
                }
        }
    }
}

// ---------------------------------------------------------------------------
// MFMA flash attention v3: 32x32x16, 128 q-rows/block, max-free softmax.
// S^T = K*Q^T so P is lane-local; P->bf16 A-frags built IN REGISTER via
// v_cvt_pk_bf16_f32 + v_permlane32_swap_b32 (no P LDS bounce).  V arrives
// pre-transposed (V^T[b][h][d][s]) and is staged like K via global_load_lds.
// K/V double-buffered, single barrier + vmcnt(0) per tile; buffer 1 aliases
// the dead Q staging area -> 33,280 B LDS, 4 blocks/CU (all 1024 resident).
// ---------------------------------------------------------------------------
__global__ __launch_bounds__(256) void attn_mfma(
    const u16* __restrict__ Q, const u16* __restrict__ K,
    const u16* __restrict__ VT, u16* __restrict__ O)
{
    __shared__ __align__(16) u16 smem[16640];   // 33,280 B
    u16* const Qs  = smem;                      // bytes [0,16384)
    u16* const Ks0 = smem + 8192;               // [16384,24576)
    u16* const Ks1 = smem;                      // alias Qs lo half [0,8192)
    u16* const Vt0 = smem + 12288;              // [24576,32768)
    u16* const Vt1 = smem + 4096;               // alias Qs hi half [8192,16384)
    float* const lS = (float*)(smem + 16384);   // [32768,33280)

    const int t    = threadIdx.x;
    const int lane = t & 63;
    const int w    = t >> 6;
    const int l31  = lane & 31;
    const int hl   = lane >> 5;         // 0/1
    const int bid  = blockIdx.x;
    const int bh   = bid & 63;
    // per-CU balanced qt map: CU hosts x, x+4, x+8, x+12 -> equal tile sums
    const int x_   = bid >> 6, g_ = x_ >> 2, r_ = x_ & 3;
    const int qt   = (g_ == 0) ? 15 - r_ : (g_ == 1) ? 8 + r_
                   : (g_ == 2) ? 4 + r_ : 3 - r_;
    const int h    = bh & (NHEAD - 1);
    const int b    = bh >> 4;
    const int q0   = qt * 128;

    const size_t gbase = ((size_t)b * SEQ) * DMODEL + h * HDIM;
    const size_t vbase = ((size_t)(b * NHEAD + h)) * HDIM * SEQ;

    const int rl  = lane >> 3;
    const int csw = (lane & 7) ^ rl;    // pre-swizzled source chunk

    // ---- prologue: stage Q (4 issues) + K/V^T tile 0 (2+2 issues)
    #pragma unroll
    for (int i = 0; i < 4; i++) {
        int row = 32 * w + 8 * i + rl;
        GLOBAL_LOAD_LDS16(Q + gbase + (size_t)(q0 + row) * DMODEL + csw * 8,
                          &Qs[(32 * w + 8 * i) * 64]);
    }
    #pragma unroll
    for (int i = 0; i < 2; i++) {
        int row = 16 * w + 8 * i + rl;
        GLOBAL_LOAD_LDS16(K + gbase + (size_t)row * DMODEL + csw * 8,
                          &Ks0[(16 * w + 8 * i) * 64]);
        GLOBAL_LOAD_LDS16(VT + vbase + (size_t)row * SEQ + csw * 8,
                          &Vt0[(16 * w + 8 * i) * 64]);
    }
    __syncthreads();

    // ---- hoist Q B-fragments: B[k][n=q], k = hl*8+e (+16*stp)
    bf16x8 qf[4];
    {
        int row = 32 * w + l31;
        #pragma unroll
        for (int s = 0; s < 4; s++) {
            int c = (hl + 2 * s) ^ (row & 7);
            qf[s] = *(const bf16x8*)&Qs[row * 64 + c * 8];
        }
    }
    __syncthreads();   // Qs dead; aliased buffer 1 may now be staged

    float lsum = 0.0f;
    f32x16 oacc[2] = {};
    const int qg   = q0 + 32 * w + l31;
    const int qmax = q0 + 32 * w + 31;

// S^T quadrant KRH: 4 MFMA, mask, exp2, tree-sum, in-register P->bf16 frags.
#define QUADRANT(KRH, F0, F1) do {                                             \
    f32x16 s_ = {};                                                            \
    __builtin_amdgcn_s_setprio(1);                                             \
    _Pragma("unroll")                                                          \
    for (int stp_ = 0; stp_ < 4; ++stp_) {                                     \
        int c_ = ((hl + 2 * stp_) ^ (l31 & 7)) * 8;                            \
        bf16x8 ka_ = *(const bf16x8*)&Ksb[(32 * (KRH) + l31) * 64 + c_];       \
        s_ = __builtin_amdgcn_mfma_f32_32x32x16_bf16(ka_, qf[stp_], s_, 0, 0, 0);\
    }                                                                          \
    __builtin_amdgcn_s_setprio(0);                                             \
    if (k0 + 32 * (KRH) + 31 > q0 + 32 * w) {                                  \
        _Pragma("unroll")                                                      \
        for (int rr_ = 0; rr_ < 16; ++rr_) {                                   \
            int krg_ = k0 + 32 * (KRH) + (rr_ & 3) + 8 * (rr_ >> 2) + 4 * hl;  \
            if (krg_ > qg) s_[rr_] = -1e30f;                                   \
        }                                                                      \
    }                                                                          \
    float pv_[16];                                                             \
    _Pragma("unroll")                                                          \
    for (int rr_ = 0; rr_ < 16; ++rr_) pv_[rr_] = __builtin_amdgcn_exp2f(s_[rr_]);\
    lsum += ((pv_[0]+pv_[1])+(pv_[2]+pv_[3])) + ((pv_[4]+pv_[5])+(pv_[6]+pv_[7]))\
          + ((pv_[8]+pv_[9])+(pv_[10]+pv_[11])) + ((pv_[12]+pv_[13])+(pv_[14]+pv_[15]));\
    u32 k01_ = cvtpk(pv_[0], pv_[1]),   k23_ = cvtpk(pv_[2], pv_[3]);          \
    u32 k45_ = cvtpk(pv_[4], pv_[5]),   k67_ = cvtpk(pv_[6], pv_[7]);          \
    u32 k89_ = cvtpk(pv_[8], pv_[9]),   kab_ = cvtpk(pv_[10], pv_[11]);        \
    u32 kcd_ = cvtpk(pv_[12], pv_[13]), kef_ = cvtpk(pv_[14], pv_[15]);        \
    PLSWAP(k01_, k45_); PLSWAP(k23_, k67_);                                    \
    PLSWAP(k89_, kcd_); PLSWAP(kab_, kef_);                                    \
    { union { u32x4 u; bf16x8 v; } c0_; c0_.u = (u32x4){k01_, k23_, k45_, k67_};\
      F0 = c0_.v; }                                                            \
    { union { u32x4 u; bf16x8 v; } c1_; c1_.u = (u32x4){k89_, kab_, kcd_, kef_};\
      F1 = c1_.v; }                                                            \
} while (0)

#define PVSTEP(STP, PF) do {                                                   \
    int c_ = ((hl + 2 * (STP)) ^ (l31 & 7)) * 8;                               \
    bf16x8 v0_ = *(const bf16x8*)&Vtb[l31 * 64 + c_];                          \
    bf16x8 v1_ = *(const bf16x8*)&Vtb[(32 + l31) * 64 + c_];                   \
    oacc[0] = __builtin_amdgcn_mfma_f32_32x32x16_bf16(PF, v0_, oacc[0], 0, 0, 0);\
    oacc[1] = __builtin_amdgcn_mfma_f32_32x32x16_bf16(PF, v1_, oacc[1], 0, 0, 0);\
} while (0)

    const int ktn = 2 * qt + 2;
    for (int kt = 0; kt < ktn; kt++) {
        const int k0 = kt * 64;
        u16* const Ksb = (kt & 1) ? Ks1 : Ks0;
        u16* const Vtb = (kt & 1) ? Vt1 : Vt0;

        // prefetch next tile into the other buffer (issue-early)
        if (kt + 1 < ktn) {
            u16* const Ksn = (kt & 1) ? Ks0 : Ks1;
            u16* const Vtn = (kt & 1) ? Vt0 : Vt1;
            const size_t kk0 = (size_t)(kt + 1) * 64;
            #pragma unroll
            for (int i = 0; i < 2; i++) {
                int row = 16 * w + 8 * i + rl;
                GLOBAL_LOAD_LDS16(K + gbase + (kk0 + row) * DMODEL + csw * 8,
                                  &Ksn[(16 * w + 8 * i) * 64]);
                GLOBAL_LOAD_LDS16(VT + vbase + (size_t)row * SEQ + kk0 + csw * 8,
                                  &Vtn[(16 * w + 8 * i) * 64]);
            }
        }

        if (k0 <= qmax) {
            const bool q2 = (k0 + 32 <= qmax);
            bf16x8 pa0, pa1, pa2, pa3;
            QUADRANT(0, pa0, pa1);
            __builtin_amdgcn_s_setprio(1);
            PVSTEP(0, pa0); PVSTEP(1, pa1);
            __builtin_amdgcn_s_setprio(0);
            if (q2) {
                QUADRANT(1, pa2, pa3);
                __builtin_amdgcn_s_setprio(1);
                PVSTEP(2, pa2); PVSTEP(3, pa3);
                __builtin_amdgcn_s_setprio(0);
            }
        }
        asm volatile("s_waitcnt vmcnt(0)" ::: "memory");
        __builtin_amdgcn_s_barrier();
    }
#undef QUADRANT
#undef PVSTEP

    // ---- finalize l (cross-half reduce, through LDS to reindex q)
    lsum += __shfl_xor(lsum, 32, 64);
    if (lane < 32) lS[32 * w + lane] = lsum;
    __syncthreads();

    // ---- writeout: O / l   (C layout: col=l31=d-local, row=(r&3)+8*(r>>2)+4*hl)
    #pragma unroll
    for (int g = 0; g < 4; g++) {
        f32x4 lv = *(const f32x4*)&lS[32 * w + 8 * g + 4 * hl];
        #pragma unroll
        for (int rr = 0; rr < 4; rr++) {
            int qg2 = q0 + 32 * w + rr + 8 * g + 4 * hl;
            float inv = 1.0f / lv[rr];
            #pragma unroll
            for (int dh = 0; dh < 2; dh++) {
                float o = oacc[dh][4 * g + rr] * inv;
                O[gbase + (size_t)qg2 * DMODEL + 32 * dh + l31] = f2bf(o);
            }
        }
    }
}

// ---------------------------------------------------------------------------
extern "C" void kernel_launch(void* const* d_in, const int* in_sizes, int n_in,
                              void* d_out, int out_size, void* d_ws, size_t ws_size,
                              hipStream_t stream)
{
    const float* x  = (const float*)d_in[0];
    const float* Wq = (const float*)d_in[1];
    const float* bq = (const float*)d_in[2];
    const float* Wk = (const float*)d_in[3];
    const float* bk = (const float*)d_in[4];
    const float* Wv = (const float*)d_in[5];
    const float* bv = (const float*)d_in[6];
    const float* Wo = (const float*)d_in[7];
    const float* bo = (const float*)d_in[8];

    u16* wsp = (u16*)d_ws;
    u16* xb  = wsp;                    // 8388608
    u16* Wqb = wsp + 8388608;          // 1048576 each
    u16* Wkb = Wqb + 1048576;
    u16* Wvb = Wkb + 1048576;
    u16* Wob = Wvb + 1048576;
    u16* Qb  = Wob + 1048576;          // 8388608 each
    u16* Kb  = Qb + 8388608;
    u16* Vb  = Kb + 8388608;           // holds V^T[b][h][d][s]
    u16* Ab  = Vb + 8388608;

    convert_inputs<<<12288, 256, 0, stream>>>(x, Wq, Wk, Wv, Wo, xb);

    gemm_mfma<1><<<768, 512, 0, stream>>>(xb, Wqb, Wkb, Wvb, bq, bk, bv,
                                          Qb, Kb, Vb, nullptr);

    attn_mfma<<<1024, 256, 0, stream>>>(Qb, Kb, Vb, Ab);

    gemm_mfma<0><<<256, 512, 0, stream>>>(Ab, Wob, nullptr, nullptr, bo, nullptr, nullptr,
                                          nullptr, nullptr, nullptr, (float*)d_out);
}